// Round 1
// baseline (122.265 us; speedup 1.0000x reference)
//
#include <hip/hip_runtime.h>
#include <math.h>

// Problem dims (fixed by setup_inputs): B=16, Cin=Cout=64, L=65536, M=512, Lh=32769
#define B_   16
#define CIN  64
#define COUT 64
#define L_   65536
#define M_   512
#define LH_  32769

// ---------------------------------------------------------------------------
// Zero-fill the entire output (134 MB). out_size = 16*64*32769 = 33555456,
// divisible by 4 -> float4 stores. Pure-store, memory-bound.
// ---------------------------------------------------------------------------
__global__ __launch_bounds__(256) void zero_out_kernel(float4* __restrict__ out, int n4) {
    int idx = blockIdx.x * blockDim.x + threadIdx.x;
    int stride = gridDim.x * blockDim.x;
    const float4 z = {0.f, 0.f, 0.f, 0.f};
    for (int j = idx; j < n4; j += stride) out[j] = z;
}

// ---------------------------------------------------------------------------
// Compute out[b, o, m] for m in [0,512):
//   m2 = (512 - m) % 512
//   acc = sum_i  x[b,i,m]*c1[m]*(w[i,o,m]+w[i,o,m2])
//              + x[b,i,m2]*c1[m2]*(w[i,o,m]-w[i,o,m2])
//   out = 0.5 * c2[m] * acc
// c1[m] = cos(2pi m / L) - sin(2pi m / L)
// c2[m] = (cos(2pi m / Lh) - sin(2pi m / Lh)) / Cin
//
// Thread tile: 4 b x 4 o outputs, one m per thread.
// Grid: 2 (m-half) x 4 (b-quad) x 16 (o-quad) = 128 blocks x 256 threads.
// ---------------------------------------------------------------------------
__global__ __launch_bounds__(256) void spectral_compute(
    const float* __restrict__ x, const float* __restrict__ w, float* __restrict__ out)
{
    const int bid = blockIdx.x;
    const int mh = bid & 1;          // m half: [0,256) or [256,512)
    const int bq = (bid >> 1) & 3;   // b quad -> b in [bq*4, bq*4+4)
    const int oq = bid >> 3;         // o quad -> o in [oq*4, oq*4+4)  (0..15)

    const int m  = mh * 256 + threadIdx.x;
    const int m2 = (M_ - m) & (M_ - 1);

    const float TWO_PI = 6.28318530717958647692f;
    const float t1  = TWO_PI * (float)m  / (float)L_;
    const float t1n = TWO_PI * (float)m2 / (float)L_;
    const float t2  = TWO_PI * (float)m  / (float)LH_;
    const float c1m = cosf(t1)  - sinf(t1);
    const float c1n = cosf(t1n) - sinf(t1n);
    const float c2  = (cosf(t2) - sinf(t2)) * (1.0f / (float)CIN);

    float acc[4][4];
    #pragma unroll
    for (int a = 0; a < 4; ++a)
        #pragma unroll
        for (int c = 0; c < 4; ++c) acc[a][c] = 0.f;

    const int b0 = bq * 4;
    const int o0 = oq * 4;

    for (int i = 0; i < CIN; ++i) {
        float xm[4], xn[4];
        #pragma unroll
        for (int bb = 0; bb < 4; ++bb) {
            const float* xr = x + ((size_t)(b0 + bb) * CIN + i) * L_;
            xm[bb] = xr[m]  * c1m;
            xn[bb] = xr[m2] * c1n;
        }
        #pragma unroll
        for (int oo = 0; oo < 4; ++oo) {
            const float* wr = w + ((size_t)i * COUT + (o0 + oo)) * M_;
            const float wm = wr[m];
            const float wn = wr[m2];
            const float ws = wm + wn;
            const float wd = wm - wn;
            #pragma unroll
            for (int bb = 0; bb < 4; ++bb)
                acc[bb][oo] += xm[bb] * ws + xn[bb] * wd;
        }
    }

    #pragma unroll
    for (int bb = 0; bb < 4; ++bb)
        #pragma unroll
        for (int oo = 0; oo < 4; ++oo)
            out[((size_t)(b0 + bb) * COUT + (o0 + oo)) * LH_ + m] = 0.5f * c2 * acc[bb][oo];
}

extern "C" void kernel_launch(void* const* d_in, const int* in_sizes, int n_in,
                              void* d_out, int out_size, void* d_ws, size_t ws_size,
                              hipStream_t stream) {
    const float* x = (const float*)d_in[0];   // (16, 64, 65536) f32
    const float* w = (const float*)d_in[1];   // (64, 64, 512)   f32
    float* out = (float*)d_out;               // (16, 64, 32769) f32

    const int n4 = out_size / 4;  // out_size = 33555456, divisible by 4
    zero_out_kernel<<<2048, 256, 0, stream>>>((float4*)out, n4);
    spectral_compute<<<128, 256, 0, stream>>>(x, w, out);
}

// Round 2
// 38.549 us; speedup vs baseline: 3.1716x; 3.1716x over previous
//
#include <hip/hip_runtime.h>
#include <math.h>

// Problem dims (fixed by setup_inputs): B=16, Cin=Cout=64, L=65536, M=512, Lh=32769
#define B_   16
#define CIN  64
#define COUT 64
#define L_   65536
#define M_   512
#define LH_  32769

#define NBLK     2048
#define NTHREADS (NBLK * 256)              // 524288
#define N4       ((B_ * COUT * LH_) / 4)   // 8388864 float4s = whole output

// ---------------------------------------------------------------------------
// One fused kernel.
// Part 1 (all 2048*256 threads): zero-fill every output element with
//   col >= 512 (col = flat % 32769). float4 fast path when the whole
//   float4 lies in [512, 32768]; per-element fallback at row boundaries.
// Part 2 (first wave of each block, 131072 threads): compute cols [0,512):
//   m2 = (512 - m) % 512
//   out[b,o,m] = 0.5*c2[m]*sum_i( x[b,i,m]*c1[m]*(w[i,o,m]+w[i,o,m2])
//                               + x[b,i,m2]*c1[m2]*(w[i,o,m]-w[i,o,m2]) )
// Stores of part 1 and part 2 are disjoint -> no intra-kernel race.
// ---------------------------------------------------------------------------
__global__ __launch_bounds__(256) void fused_spectral(
    const float* __restrict__ x, const float* __restrict__ w, float* __restrict__ out)
{
    const int tid = blockIdx.x * 256 + threadIdx.x;

    // ---- Part 1: streaming zero-fill of the col>=512 region (132 MB)
    for (int j = tid; j < N4; j += NTHREADS) {
        const unsigned flat = (unsigned)j * 4u;
        const unsigned row  = flat / (unsigned)LH_;           // magic-mul, const divisor
        const unsigned col  = flat - row * (unsigned)LH_;
        if (col >= (unsigned)M_ && col <= (unsigned)(LH_ - 4)) {
            const float4 z = {0.f, 0.f, 0.f, 0.f};
            reinterpret_cast<float4*>(out)[j] = z;
        } else {
            #pragma unroll
            for (int e = 0; e < 4; ++e) {
                const unsigned f  = flat + (unsigned)e;
                const unsigned r2 = f / (unsigned)LH_;
                const unsigned c2_ = f - r2 * (unsigned)LH_;
                if (c2_ >= (unsigned)M_) out[f] = 0.f;
            }
        }
    }

    // ---- Part 2: compute region, one wave per block
    if (threadIdx.x >= 64) return;
    const int ctid = blockIdx.x * 64 + (int)threadIdx.x;  // 0..131071
    const int m  = ctid & (M_ - 1);          // wave-contiguous -> coalesced
    const int og = (ctid >> 9) & 15;
    const int b  = ctid >> 13;               // 0..15
    const int o0 = og * 4;
    const int m2 = (M_ - m) & (M_ - 1);

    const float TWO_PI = 6.28318530717958647692f;
    const float t1  = TWO_PI * (float)m  / (float)L_;
    const float t1n = TWO_PI * (float)m2 / (float)L_;
    const float t2  = TWO_PI * (float)m  / (float)LH_;
    const float c1m = cosf(t1)  - sinf(t1);
    const float c1n = cosf(t1n) - sinf(t1n);
    const float c2  = (cosf(t2) - sinf(t2)) * (1.0f / (float)CIN);

    float acc[4] = {0.f, 0.f, 0.f, 0.f};
    const float* xb = x + (size_t)b * CIN * L_;
    for (int i = 0; i < CIN; ++i) {
        const float xm = xb[(size_t)i * L_ + m]  * c1m;
        const float xn = xb[(size_t)i * L_ + m2] * c1n;
        const float* wr = w + ((size_t)i * COUT + o0) * M_;
        #pragma unroll
        for (int oo = 0; oo < 4; ++oo) {
            const float wm = wr[(size_t)oo * M_ + m];
            const float wn = wr[(size_t)oo * M_ + m2];
            acc[oo] += xm * (wm + wn) + xn * (wm - wn);
        }
    }

    #pragma unroll
    for (int oo = 0; oo < 4; ++oo)
        out[(size_t)(b * COUT + o0 + oo) * LH_ + m] = 0.5f * c2 * acc[oo];
}

extern "C" void kernel_launch(void* const* d_in, const int* in_sizes, int n_in,
                              void* d_out, int out_size, void* d_ws, size_t ws_size,
                              hipStream_t stream) {
    const float* x = (const float*)d_in[0];   // (16, 64, 65536) f32
    const float* w = (const float*)d_in[1];   // (64, 64, 512)   f32
    float* out = (float*)d_out;               // (16, 64, 32769) f32

    fused_spectral<<<NBLK, 256, 0, stream>>>(x, w, out);
}